// Round 1
// baseline (72.497 us; speedup 1.0000x reference)
//
#include <hip/hip_runtime.h>
#include <hip/hip_bf16.h>

// out[b,i,j,o] = (x[b,min]·M_lo[o] + s_lo[o]) + (x[b,max]·M_hi[o] + s_hi[o])
// where M_lo[o] = W1^T Wc[o,:100], M_hi[o] = W1^T Wc[o,100:],
//       s_lo[o] = b1·Wc[o,:100] + bc[o], s_hi[o] = b1·Wc[o,100:].

#define NA 13
#define DM 512
#define NOH 8   // 4 outputs x {lo,hi}

__global__ __launch_bounds__(512) void precompute_M(
    const float* __restrict__ W1, const float* __restrict__ b1,
    const float* __restrict__ Wc, const float* __restrict__ bc,
    float* __restrict__ M, float* __restrict__ s) {
    int oh = blockIdx.x;          // 0..7: oh = half*4 + o
    int o = oh & 3, half = oh >> 2;
    int d = threadIdx.x;          // 0..511
    const float* wc = Wc + o * 200 + half * 100;
    float acc = 0.f;
    for (int c = 0; c < 100; ++c)
        acc = fmaf(wc[c], W1[c * DM + d], acc);
    M[oh * DM + d] = acc;
    if (d == 0) {
        float sv = (half == 0) ? bc[o] : 0.f;
        for (int c = 0; c < 100; ++c) sv = fmaf(wc[c], b1[c], sv);
        s[oh] = sv;
    }
}

__global__ __launch_bounds__(256) void edge_main(
    const float* __restrict__ x, const float* __restrict__ M,
    const float* __restrict__ s, float* __restrict__ out) {
    const int b = blockIdx.x;
    const int lane = threadIdx.x & 63;
    const int wave = threadIdx.x >> 6;

    // Per-lane M slices: lane covers d = lane*4..+3 and d = 256+lane*4..+3
    float4 mA[NOH], mB[NOH];
#pragma unroll
    for (int oh = 0; oh < NOH; ++oh) {
        mA[oh] = *(const float4*)(M + oh * DM + lane * 4);
        mB[oh] = *(const float4*)(M + oh * DM + 256 + lane * 4);
    }
    float sreg[NOH];
#pragma unroll
    for (int oh = 0; oh < NOH; ++oh) sreg[oh] = s[oh];

    __shared__ float G[NA][NOH];

    const float* xb = x + (size_t)b * (NA * DM);
    for (int a = wave; a < NA; a += 4) {
        float4 xA = *(const float4*)(xb + a * DM + lane * 4);
        float4 xB = *(const float4*)(xb + a * DM + 256 + lane * 4);
        float acc[NOH];
#pragma unroll
        for (int oh = 0; oh < NOH; ++oh) {
            float v = xA.x * mA[oh].x;
            v = fmaf(xA.y, mA[oh].y, v);
            v = fmaf(xA.z, mA[oh].z, v);
            v = fmaf(xA.w, mA[oh].w, v);
            v = fmaf(xB.x, mB[oh].x, v);
            v = fmaf(xB.y, mB[oh].y, v);
            v = fmaf(xB.z, mB[oh].z, v);
            v = fmaf(xB.w, mB[oh].w, v);
            acc[oh] = v;
        }
        // butterfly reduce across the 64 lanes
#pragma unroll
        for (int m = 32; m >= 1; m >>= 1) {
#pragma unroll
            for (int oh = 0; oh < NOH; ++oh)
                acc[oh] += __shfl_xor(acc[oh], m, 64);
        }
        if (lane == 0) {
#pragma unroll
            for (int oh = 0; oh < NOH; ++oh)
                G[a][oh] = acc[oh] + sreg[oh];
        }
    }
    __syncthreads();

    // 13*13*4 = 676 outputs, coalesced
    float* outb = out + (size_t)b * (NA * NA * 4);
    for (int e = threadIdx.x; e < NA * NA * 4; e += 256) {
        int o = e & 3;
        int ij = e >> 2;          // 0..168
        int i = ij / NA, j = ij % NA;
        int lo = i < j ? i : j;
        int hi = i < j ? j : i;
        outb[e] = G[lo][o] + G[hi][4 + o];
    }
}

extern "C" void kernel_launch(void* const* d_in, const int* in_sizes, int n_in,
                              void* d_out, int out_size, void* d_ws, size_t ws_size,
                              hipStream_t stream) {
    const float* x  = (const float*)d_in[0];
    const float* W1 = (const float*)d_in[1];
    const float* b1 = (const float*)d_in[2];
    const float* Wc = (const float*)d_in[3];
    const float* bc = (const float*)d_in[4];
    float* out = (float*)d_out;

    float* M = (float*)d_ws;            // 8*512 floats = 16 KB
    float* s = M + NOH * DM;            // 8 floats

    precompute_M<<<8, 512, 0, stream>>>(W1, b1, Wc, bc, M, s);
    edge_main<<<8192, 256, 0, stream>>>(x, M, s, out);
}

// Round 2
// 47.973 us; speedup vs baseline: 1.5112x; 1.5112x over previous
//
#include <hip/hip_runtime.h>
#include <hip/hip_bf16.h>

// out[b,i,j,o] = (x[b,min]·M_lo[o] + s_lo[o]) + (x[b,max]·M_hi[o] + s_hi[o])
// where M_lo[o] = W1^T Wc[o,:100], M_hi[o] = W1^T Wc[o,100:],
//       s_lo[o] = b1·Wc[o,:100] + bc[o], s_hi[o] = b1·Wc[o,100:].

#define NA 13
#define DM 512
#define NOH 8   // 4 outputs x {lo,hi}

__global__ __launch_bounds__(512) void precompute_M(
    const float* __restrict__ W1, const float* __restrict__ b1,
    const float* __restrict__ Wc, const float* __restrict__ bc,
    float* __restrict__ M, float* __restrict__ s) {
    int oh = blockIdx.x;          // 0..7: oh = half*4 + o
    int o = oh & 3, half = oh >> 2;
    int d = threadIdx.x;          // 0..511
    const float* wc = Wc + o * 200 + half * 100;
    float acc = 0.f;
    for (int c = 0; c < 100; ++c)
        acc = fmaf(wc[c], W1[c * DM + d], acc);
    M[oh * DM + d] = acc;
    if (d == 0) {
        float sv = (half == 0) ? bc[o] : 0.f;
        for (int c = 0; c < 100; ++c) sv = fmaf(wc[c], b1[c], sv);
        s[oh] = sv;
    }
}

__global__ __launch_bounds__(256) void edge_main(
    const float* __restrict__ x, const float* __restrict__ M,
    const float* __restrict__ s, float* __restrict__ out) {
    const int b = blockIdx.x;
    const int lane = threadIdx.x & 63;
    const int wave = threadIdx.x >> 6;

    // Per-lane M slices: lane covers d = lane*4..+3 and d = 256+lane*4..+3
    float4 mA[NOH], mB[NOH];
#pragma unroll
    for (int oh = 0; oh < NOH; ++oh) {
        mA[oh] = *(const float4*)(M + oh * DM + lane * 4);
        mB[oh] = *(const float4*)(M + oh * DM + 256 + lane * 4);
    }
    const float s_lane = s[lane & 7];

    const bool m1 = (lane & 1) != 0;
    const bool m2 = (lane & 2) != 0;
    const bool m4 = (lane & 4) != 0;

    __shared__ float G[NA][NOH];

    const float* xb = x + (size_t)b * (NA * DM);
#pragma unroll
    for (int k = 0; k < 4; ++k) {
        const int a = wave + 4 * k;
        if (a < NA) {
            float4 xA = *(const float4*)(xb + a * DM + lane * 4);
            float4 xB = *(const float4*)(xb + a * DM + 256 + lane * 4);
            float acc[NOH];
#pragma unroll
            for (int oh = 0; oh < NOH; ++oh) {
                float v = xA.x * mA[oh].x;
                v = fmaf(xA.y, mA[oh].y, v);
                v = fmaf(xA.z, mA[oh].z, v);
                v = fmaf(xA.w, mA[oh].w, v);
                v = fmaf(xB.x, mB[oh].x, v);
                v = fmaf(xB.y, mB[oh].y, v);
                v = fmaf(xB.z, mB[oh].z, v);
                v = fmaf(xB.w, mB[oh].w, v);
                acc[oh] = v;
            }
            // transpose-reduce: after 3 merge steps lane l holds oh=(l&7)
            // partial over its 8-lane group; 3 butterflies finish 64 lanes.
            float r1[4];
#pragma unroll
            for (int q = 0; q < 4; ++q) {
                float keep = m1 ? acc[2 * q + 1] : acc[2 * q];
                float send = m1 ? acc[2 * q]     : acc[2 * q + 1];
                r1[q] = keep + __shfl_xor(send, 1, 64);
            }
            float r2[2];
#pragma unroll
            for (int q = 0; q < 2; ++q) {
                float keep = m2 ? r1[2 * q + 1] : r1[2 * q];
                float send = m2 ? r1[2 * q]     : r1[2 * q + 1];
                r2[q] = keep + __shfl_xor(send, 2, 64);
            }
            {
                float keep = m4 ? r2[1] : r2[0];
                float send = m4 ? r2[0] : r2[1];
                float t = keep + __shfl_xor(send, 4, 64);
                t += __shfl_xor(t, 8, 64);
                t += __shfl_xor(t, 16, 64);
                t += __shfl_xor(t, 32, 64);
                if (lane < NOH) G[a][lane] = t + s_lane;
            }
        }
    }
    __syncthreads();

    // 13*13 pairs, one float4 (4 outputs) per thread, coalesced
    const int t = threadIdx.x;
    if (t < NA * NA) {
        int i = t / NA, j = t % NA;
        int lo = i < j ? i : j;
        int hi = i < j ? j : i;
        float4 v;
        v.x = G[lo][0] + G[hi][4];
        v.y = G[lo][1] + G[hi][5];
        v.z = G[lo][2] + G[hi][6];
        v.w = G[lo][3] + G[hi][7];
        ((float4*)(out + (size_t)b * (NA * NA * 4)))[t] = v;
    }
}

extern "C" void kernel_launch(void* const* d_in, const int* in_sizes, int n_in,
                              void* d_out, int out_size, void* d_ws, size_t ws_size,
                              hipStream_t stream) {
    const float* x  = (const float*)d_in[0];
    const float* W1 = (const float*)d_in[1];
    const float* b1 = (const float*)d_in[2];
    const float* Wc = (const float*)d_in[3];
    const float* bc = (const float*)d_in[4];
    float* out = (float*)d_out;

    float* M = (float*)d_ws;            // 8*512 floats = 16 KB
    float* s = M + NOH * DM;            // 8 floats

    precompute_M<<<8, 512, 0, stream>>>(W1, b1, Wc, bc, M, s);
    edge_main<<<8192, 256, 0, stream>>>(x, M, s, out);
}